// Round 1
// 678.942 us; speedup vs baseline: 1.0016x; 1.0016x over previous
//
#include <hip/hip_runtime.h>

#define D_OUT 4096
#define D_IN  4096
#define RANK  64
#define NNZ   1000000
#define MTOT  8192   // 4*2048
#define KDIM  4096
#define NDIM  4096

#define BM 256
#define BN 256
#define BK 64
#define NT (KDIM / BK)   // 64 K-tiles

typedef __bf16 bf16_t;
typedef __bf16 bf16x8 __attribute__((ext_vector_type(8)));
typedef __bf16 bf16x4 __attribute__((ext_vector_type(4)));
typedef float  f32x4  __attribute__((ext_vector_type(4)));

// ---------------- kernel 1: scatter-add sparse COO into S ----------------
__global__ __launch_bounds__(256) void scatter_sp_kernel(
    const float* __restrict__ vals, const int* __restrict__ idx,
    float* __restrict__ S) {
  int i = blockIdx.x * 256 + threadIdx.x;
  if (i < NNZ) {
    int r = idx[i];
    int c = idx[NNZ + i];
    atomicAdd(&S[(size_t)r * D_IN + c], vals[i]);
  }
}

// ---------------- kernel 2: weffb = bf16(W + A@Bmat + S) ----------------
__global__ __launch_bounds__(256) void build_weff_fused_kernel(
    const float* __restrict__ W, const float* __restrict__ A,
    const float* __restrict__ B, const float* __restrict__ S,
    bf16_t* __restrict__ outb) {
  __shared__ float sA[64 * 64];
  const int o0 = blockIdx.y * 64;
  const int d0 = blockIdx.x * 128;
  const int t  = threadIdx.x;
  const int td = t & 31;     // d-group
  const int to = t >> 5;     // o-group 0..7
  const int d  = d0 + td * 4;

  #pragma unroll
  for (int i = 0; i < 16; ++i)
    sA[t + i * 256] = A[(size_t)o0 * 64 + t + i * 256];
  __syncthreads();

  f32x4 acc[8] = {};
  for (int r = 0; r < 64; ++r) {
    f32x4 bv = *(const f32x4*)&B[(size_t)r * D_IN + d];
    #pragma unroll
    for (int j = 0; j < 8; ++j) {
      float a = sA[(to * 8 + j) * 64 + r];
      acc[j] += a * bv;
    }
  }

  #pragma unroll
  for (int j = 0; j < 8; ++j) {
    int o = o0 + to * 8 + j;
    size_t idx = (size_t)o * D_IN + d;
    f32x4 wv = *(const f32x4*)&W[idx];
    f32x4 sv = *(const f32x4*)&S[idx];
    f32x4 v  = wv + sv + acc[j];
    bf16x4 ob;
    ob[0] = (bf16_t)v[0]; ob[1] = (bf16_t)v[1];
    ob[2] = (bf16_t)v[2]; ob[3] = (bf16_t)v[3];
    *(bf16x4*)&outb[idx] = ob;
  }
}

// ---------------- kernel 3: fp32 -> bf16 cast (8 elems/thread) ----------------
__global__ __launch_bounds__(256) void cvt_bf16_kernel(
    const float* __restrict__ in, bf16_t* __restrict__ out, int n8) {
  int i = blockIdx.x * 256 + threadIdx.x;
  if (i >= n8) return;
  const f32x4* p = (const f32x4*)in + (size_t)i * 2;
  f32x4 a = p[0], b = p[1];
  bf16x8 o;
  o[0] = (bf16_t)a[0]; o[1] = (bf16_t)a[1]; o[2] = (bf16_t)a[2]; o[3] = (bf16_t)a[3];
  o[4] = (bf16_t)b[0]; o[5] = (bf16_t)b[1]; o[6] = (bf16_t)b[2]; o[7] = (bf16_t)b[3];
  *((bf16x8*)out + i) = o;
}

// ---------------- kernel 4: 256x256 8-phase deep-pipelined GEMM ----------------
// out[M][N] = Xb[M][K] @ Wb[N][K]^T, bf16 in / f32 out.
// T1 XCD swizzle + T3/T4 counted-vmcnt 8-phase + T5 setprio.
// LDS: chunk-major [buf][A|B][kchunk(16k)][256 rows][16 k] -> each 8KB chunk is
// one linear global_load_lds round AND the ds_read_b128 pattern
// (slot = (lr&3)*2 + (lq&1)) is bank-minimal with NO swizzle.
//
// Schedule per K-tile (4 phases, stage tile t+1 into other buffer):
//  P0: rdA[0-3]ks0 + rdB ks0 | stage q0      | bar lgkm0 | 16 MFMA | bar
//  P1: rdA[4-7]ks0           | stage q1 vm(4)| bar lgkm0 | 16 MFMA | bar
//  P2: rdA[0-3]ks1 + rdB ks1 | stage q2      | bar lgkm0 | 16 MFMA | bar
//  P3: rdA[4-7]ks1           | stage q3 vm(4)| bar lgkm0 | 16 MFMA | bar
// vmcnt(4) at P1 completes this tile's ks1 chunks; at P3 completes next tile's
// ks0 chunks. 4 loads always stay in flight (never vmcnt 0 in the loop).

#define VMCNT4() asm volatile("s_waitcnt vmcnt(4)" ::: "memory")
#define VMCNT0() asm volatile("s_waitcnt vmcnt(0)" ::: "memory")
#define LGKM0()  asm volatile("s_waitcnt lgkmcnt(0)" ::: "memory")
#define BARR()   do { asm volatile("" ::: "memory"); \
                      __builtin_amdgcn_s_barrier(); \
                      asm volatile("" ::: "memory"); } while (0)

__global__ __launch_bounds__(512, 2) void gemm256_kernel(
    const bf16_t* __restrict__ Xb, const bf16_t* __restrict__ Wb,
    float* __restrict__ out) {
  // [buf][A=0/B=1][kchunk q][row*16 + k]   = 128 KiB
  __shared__ bf16_t lds[2][2][4][256 * 16];

  const int t    = threadIdx.x;
  const int w    = t >> 6;
  const int lane = t & 63;
  const int lr   = lane & 15;
  const int lq   = lane >> 4;
  const int qsel = lq >> 1;        // which 16-k chunk within the 32-k step
  const int kh8  = (lq & 1) * 8;   // 8-elem half within the chunk row

  // T1: XCD-aware swizzle over the 512-block grid (512 % 8 == 0 -> simple form)
  const int bid  = blockIdx.x;
  const int wgid = (bid & 7) * 64 + (bid >> 3);
  const int m0 = (wgid >> 4) * BM;   // 32 m-tiles (consecutive wgids share m-panel)
  const int n0 = (wgid & 15) * BN;   // 16 n-tiles

  const int wm = (w >> 2) * 128;     // 2 M-wave-rows
  const int wn = (w & 3) * 64;       // 4 N-wave-cols

  // staging: thread t owns granule (row = t>>1, k-half = t&1) of each chunk
  const int sr  = t >> 1;
  const int skh = t & 1;
  const size_t aBase = (size_t)(m0 + sr) * KDIM + skh * 8;
  const size_t bBase = (size_t)(n0 + sr) * KDIM + skh * 8;

#define STAGE_A(NXT, TKN, Q)                                                   \
  __builtin_amdgcn_global_load_lds(                                            \
      (const __attribute__((address_space(1))) void*)(const void*)             \
          (Xb + aBase + (size_t)(TKN) * BK + (Q) * 16),                        \
      (__attribute__((address_space(3))) void*)(void*)&lds[NXT][0][Q][t * 8],  \
      16, 0, 0)
#define STAGE_B(NXT, TKN, Q)                                                   \
  __builtin_amdgcn_global_load_lds(                                            \
      (const __attribute__((address_space(1))) void*)(const void*)             \
          (Wb + bBase + (size_t)(TKN) * BK + (Q) * 16),                        \
      (__attribute__((address_space(3))) void*)(void*)&lds[NXT][1][Q][t * 8],  \
      16, 0, 0)

#define RD_A(IB, CUR, KS) do {                                                 \
    _Pragma("unroll")                                                          \
    for (int i_ = 0; i_ < 4; ++i_)                                             \
      av[i_] = *(const bf16x8*)&lds[CUR][0][(KS) * 2 + qsel]                   \
                   [(wm + ((IB) + i_) * 16 + lr) * 16 + kh8];                  \
  } while (0)
#define RD_B(CUR, KS) do {                                                     \
    _Pragma("unroll")                                                          \
    for (int j_ = 0; j_ < 4; ++j_)                                             \
      bv[j_] = *(const bf16x8*)&lds[CUR][1][(KS) * 2 + qsel]                   \
                   [(wn + j_ * 16 + lr) * 16 + kh8];                           \
  } while (0)

#define MFMA_BLOCK(IB) do {                                                    \
    __builtin_amdgcn_s_setprio(1);                                             \
    _Pragma("unroll")                                                          \
    for (int i_ = 0; i_ < 4; ++i_)                                             \
      _Pragma("unroll")                                                        \
      for (int j_ = 0; j_ < 4; ++j_)                                           \
        acc[(IB) + i_][j_] = __builtin_amdgcn_mfma_f32_16x16x32_bf16(          \
            av[i_], bv[j_], acc[(IB) + i_][j_], 0, 0, 0);                      \
    __builtin_amdgcn_s_setprio(0);                                             \
  } while (0)

#define GEMM_TILE(CUR, NXT, TKN, STG) do {                                     \
    /* P0 */                                                                   \
    RD_A(0, CUR, 0); RD_B(CUR, 0);                                             \
    if (STG) { STAGE_A(NXT, TKN, 0); STAGE_B(NXT, TKN, 0); }                   \
    BARR(); LGKM0(); __builtin_amdgcn_sched_barrier(0);                        \
    MFMA_BLOCK(0);                                                             \
    BARR();                                                                    \
    /* P1 */                                                                   \
    RD_A(4, CUR, 0);                                                           \
    if (STG) { STAGE_A(NXT, TKN, 1); STAGE_B(NXT, TKN, 1); VMCNT4(); }         \
    else     { VMCNT0(); }                                                     \
    BARR(); LGKM0(); __builtin_amdgcn_sched_barrier(0);                        \
    MFMA_BLOCK(4);                                                             \
    BARR();                                                                    \
    /* P2 */                                                                   \
    RD_A(0, CUR, 1); RD_B(CUR, 1);                                             \
    if (STG) { STAGE_A(NXT, TKN, 2); STAGE_B(NXT, TKN, 2); }                   \
    BARR(); LGKM0(); __builtin_amdgcn_sched_barrier(0);                        \
    MFMA_BLOCK(0);                                                             \
    BARR();                                                                    \
    /* P3 */                                                                   \
    RD_A(4, CUR, 1);                                                           \
    if (STG) { STAGE_A(NXT, TKN, 3); STAGE_B(NXT, TKN, 3); VMCNT4(); }         \
    BARR(); LGKM0(); __builtin_amdgcn_sched_barrier(0);                        \
    MFMA_BLOCK(4);                                                             \
    BARR();                                                                    \
  } while (0)

  f32x4 acc[8][4] = {};
  bf16x8 av[4], bv[4];

  // prologue: stage tile 0 (ks0 chunks first), keep ks1 chunks in flight
  STAGE_A(0, 0, 0); STAGE_B(0, 0, 0);
  STAGE_A(0, 0, 1); STAGE_B(0, 0, 1);
  STAGE_A(0, 0, 2); STAGE_B(0, 0, 2);
  STAGE_A(0, 0, 3); STAGE_B(0, 0, 3);
  VMCNT4();
  BARR();

  for (int tk = 0; tk < NT - 1; ++tk) {
    const int cur = tk & 1;
    GEMM_TILE(cur, cur ^ 1, tk + 1, 1);
  }
  // epilogue tile (NT-1 = 63 -> cur = 1), no staging
  GEMM_TILE(1, 0, 0, 0);

  // C-write: C row = lq*4+rr, C col = lr (verified layout, same as prior kernel)
  #pragma unroll
  for (int i = 0; i < 8; ++i)
    #pragma unroll
    for (int j = 0; j < 4; ++j)
      #pragma unroll
      for (int rr = 0; rr < 4; ++rr) {
        int mm = m0 + wm + i * 16 + lq * 4 + rr;
        int nn = n0 + wn + j * 16 + lr;
        out[(size_t)mm * NDIM + nn] = acc[i][j][rr];
      }

#undef STAGE_A
#undef STAGE_B
#undef RD_A
#undef RD_B
#undef MFMA_BLOCK
#undef GEMM_TILE
}

extern "C" void kernel_launch(void* const* d_in, const int* in_sizes, int n_in,
                              void* d_out, int out_size, void* d_ws, size_t ws_size,
                              hipStream_t stream) {
  const float* x  = (const float*)d_in[0];   // [4,2048,4096] fp32
  const float* W  = (const float*)d_in[1];   // [4096,4096]
  const float* A  = (const float*)d_in[2];   // [4096,64]
  const float* B  = (const float*)d_in[3];   // [64,4096]
  const float* sv = (const float*)d_in[4];   // [1e6]
  const int*   si = (const int*)d_in[5];     // [2,1e6]
  float* out = (float*)d_out;

  // workspace: S f32 (64MB) | weff bf16 (32MB) | x bf16 (64MB)
  float*  S     = (float*)d_ws;
  bf16_t* weffb = (bf16_t*)(S + (size_t)D_OUT * D_IN);
  bf16_t* xb    = weffb + (size_t)D_OUT * D_IN;

  hipMemsetAsync(S, 0, (size_t)D_OUT * D_IN * sizeof(float), stream);
  scatter_sp_kernel<<<(NNZ + 255) / 256, 256, 0, stream>>>(sv, si, S);
  build_weff_fused_kernel<<<dim3(D_IN / 128, D_OUT / 64), 256, 0, stream>>>(W, A, B, S, weffb);
  cvt_bf16_kernel<<<(MTOT * KDIM / 8) / 256, 256, 0, stream>>>(x, xb, MTOT * KDIM / 8);
  gemm256_kernel<<<dim3((MTOT / BM) * (NDIM / BN)), 512, 0, stream>>>(xb, weffb, out);
}

// Round 2
// 675.052 us; speedup vs baseline: 1.0074x; 1.0058x over previous
//
#include <hip/hip_runtime.h>

#define D_OUT 4096
#define D_IN  4096
#define RANK  64
#define NNZ   1000000
#define MTOT  8192   // 4*2048
#define KDIM  4096
#define NDIM  4096

#define BM 256
#define BN 256
#define BK 64
#define NT (KDIM / BK)   // 64 K-tiles

typedef __bf16 bf16_t;
typedef __bf16 bf16x8 __attribute__((ext_vector_type(8)));
typedef __bf16 bf16x4 __attribute__((ext_vector_type(4)));
typedef float  f32x4  __attribute__((ext_vector_type(4)));

// ---------------- kernel 1: scatter-add sparse COO into S ----------------
__global__ __launch_bounds__(256) void scatter_sp_kernel(
    const float* __restrict__ vals, const int* __restrict__ idx,
    float* __restrict__ S) {
  int i = blockIdx.x * 256 + threadIdx.x;
  if (i < NNZ) {
    int r = idx[i];
    int c = idx[NNZ + i];
    atomicAdd(&S[(size_t)r * D_IN + c], vals[i]);
  }
}

// ------- kernel 2: fused {weffb = bf16(W + A@Bmat + S)} + {xb = bf16(x)} -------
// blocks [0, 2048): build_weff tile (o 64 x d 128); blocks [2048, 18432): cvt.
__global__ __launch_bounds__(256) void build_weff_cvt_kernel(
    const float* __restrict__ W, const float* __restrict__ A,
    const float* __restrict__ B, const float* __restrict__ S,
    bf16_t* __restrict__ outb, const float* __restrict__ x,
    bf16_t* __restrict__ xb) {
  __shared__ float sA[64 * 64];
  const int t = threadIdx.x;

  if (blockIdx.x >= 2048) {
    // ---- cvt part: 16384 blocks * 256 threads * 8 elems ----
    int i = (blockIdx.x - 2048) * 256 + t;
    const f32x4* p = (const f32x4*)x + (size_t)i * 2;
    f32x4 a = p[0], b = p[1];
    bf16x8 o;
    o[0] = (bf16_t)a[0]; o[1] = (bf16_t)a[1]; o[2] = (bf16_t)a[2]; o[3] = (bf16_t)a[3];
    o[4] = (bf16_t)b[0]; o[5] = (bf16_t)b[1]; o[6] = (bf16_t)b[2]; o[7] = (bf16_t)b[3];
    *((bf16x8*)xb + i) = o;
    return;
  }

  // ---- build part: grid (32 d-tiles) x (64 o-tiles) ----
  const int o0 = (blockIdx.x >> 5) * 64;
  const int d0 = (blockIdx.x & 31) * 128;
  const int td = t & 31;     // d-group
  const int to = t >> 5;     // o-group 0..7
  const int d  = d0 + td * 4;

  #pragma unroll
  for (int i = 0; i < 16; ++i)
    sA[t + i * 256] = A[(size_t)o0 * 64 + t + i * 256];
  __syncthreads();

  f32x4 acc[8] = {};
  for (int r = 0; r < 64; ++r) {
    f32x4 bv = *(const f32x4*)&B[(size_t)r * D_IN + d];
    #pragma unroll
    for (int j = 0; j < 8; ++j) {
      float a = sA[(to * 8 + j) * 64 + r];
      acc[j] += a * bv;
    }
  }

  #pragma unroll
  for (int j = 0; j < 8; ++j) {
    int o = o0 + to * 8 + j;
    size_t idx = (size_t)o * D_IN + d;
    f32x4 wv = *(const f32x4*)&W[idx];
    f32x4 sv = *(const f32x4*)&S[idx];
    f32x4 v  = wv + sv + acc[j];
    bf16x4 ob;
    ob[0] = (bf16_t)v[0]; ob[1] = (bf16_t)v[1];
    ob[2] = (bf16_t)v[2]; ob[3] = (bf16_t)v[3];
    *(bf16x4*)&outb[idx] = ob;
  }
}

// ---------------- kernel 3: 256x256 8-phase deep-pipelined GEMM ----------------
// out[M][N] = Xb[M][K] @ Wb[N][K]^T, bf16 in / f32 out.
// R2 fix: raw s_barrier + bare counted s_waitcnt, pinned with sched_barrier(0)
// (compile-time wall, no waitcnt side effects). R1's asm "memory" clobbers made
// SIInsertWaitcnts drain vmcnt(0) at every phase -> drain-mode (MfmaUtil 33%).
//
// LDS: chunk-major [buf][A|B][kchunk(16k)][256 rows][16 k]; each 8KB chunk is one
// linear global_load_lds round; ds_read_b128 pattern is bank-conflict-free
// (measured 0 conflicts).
//
// Per K-tile (4 phases, stage tile t+1 into other buffer):
//  P0: rdA[0-3]ks0 + rdB ks0 | stage q0      | bar lgkm0 | 16 MFMA | bar
//  P1: rdA[4-7]ks0           | stage q1 vm(4)| bar lgkm0 | 16 MFMA | bar
//  P2: rdA[0-3]ks1 + rdB ks1 | stage q2      | bar lgkm0 | 16 MFMA | bar
//  P3: rdA[4-7]ks1           | stage q3 vm(4)| bar lgkm0 | 16 MFMA | bar
// vmcnt(4) at P1 completes this tile's ks1 chunks; at P3 completes next tile's
// ks0 chunks. 4 loads always stay in flight (never vmcnt 0 in the loop).

#define SBAR()   __builtin_amdgcn_sched_barrier(0)
#define VMCNT4() do { asm volatile("s_waitcnt vmcnt(4)"); SBAR(); } while (0)
#define VMCNT0() do { asm volatile("s_waitcnt vmcnt(0)"); SBAR(); } while (0)
#define LGKM0()  do { asm volatile("s_waitcnt lgkmcnt(0)"); SBAR(); } while (0)
#define BARR()   do { SBAR(); __builtin_amdgcn_s_barrier(); SBAR(); } while (0)

__global__ __launch_bounds__(512, 2) void gemm256_kernel(
    const bf16_t* __restrict__ Xb, const bf16_t* __restrict__ Wb,
    float* __restrict__ out) {
  // [buf][A=0/B=1][kchunk q][row*16 + k]   = 128 KiB
  __shared__ bf16_t lds[2][2][4][256 * 16];

  const int t    = threadIdx.x;
  const int w    = t >> 6;
  const int lane = t & 63;
  const int lr   = lane & 15;
  const int lq   = lane >> 4;
  const int qsel = lq >> 1;        // which 16-k chunk within the 32-k step
  const int kh8  = (lq & 1) * 8;   // 8-elem half within the chunk row

  // T1: XCD-aware swizzle over the 512-block grid (512 % 8 == 0 -> simple form)
  const int bid  = blockIdx.x;
  const int wgid = (bid & 7) * 64 + (bid >> 3);
  const int m0 = (wgid >> 4) * BM;   // 32 m-tiles (consecutive wgids share m-panel)
  const int n0 = (wgid & 15) * BN;   // 16 n-tiles

  const int wm = (w >> 2) * 128;     // 2 M-wave-rows
  const int wn = (w & 3) * 64;       // 4 N-wave-cols

  // staging: thread t owns granule (row = t>>1, k-half = t&1) of each chunk
  const int sr  = t >> 1;
  const int skh = t & 1;
  const size_t aBase = (size_t)(m0 + sr) * KDIM + skh * 8;
  const size_t bBase = (size_t)(n0 + sr) * KDIM + skh * 8;

#define STAGE_A(NXT, TKN, Q)                                                   \
  __builtin_amdgcn_global_load_lds(                                            \
      (const __attribute__((address_space(1))) void*)(const void*)             \
          (Xb + aBase + (size_t)(TKN) * BK + (Q) * 16),                        \
      (__attribute__((address_space(3))) void*)(void*)&lds[NXT][0][Q][t * 8],  \
      16, 0, 0)
#define STAGE_B(NXT, TKN, Q)                                                   \
  __builtin_amdgcn_global_load_lds(                                            \
      (const __attribute__((address_space(1))) void*)(const void*)             \
          (Wb + bBase + (size_t)(TKN) * BK + (Q) * 16),                        \
      (__attribute__((address_space(3))) void*)(void*)&lds[NXT][1][Q][t * 8],  \
      16, 0, 0)

#define RD_A(IB, CUR, KS) do {                                                 \
    _Pragma("unroll")                                                          \
    for (int i_ = 0; i_ < 4; ++i_)                                             \
      av[i_] = *(const bf16x8*)&lds[CUR][0][(KS) * 2 + qsel]                   \
                   [(wm + ((IB) + i_) * 16 + lr) * 16 + kh8];                  \
  } while (0)
#define RD_B(CUR, KS) do {                                                     \
    _Pragma("unroll")                                                          \
    for (int j_ = 0; j_ < 4; ++j_)                                             \
      bv[j_] = *(const bf16x8*)&lds[CUR][1][(KS) * 2 + qsel]                   \
                   [(wn + j_ * 16 + lr) * 16 + kh8];                           \
  } while (0)

#define MFMA_BLOCK(IB) do {                                                    \
    __builtin_amdgcn_s_setprio(1);                                             \
    _Pragma("unroll")                                                          \
    for (int i_ = 0; i_ < 4; ++i_)                                             \
      _Pragma("unroll")                                                        \
      for (int j_ = 0; j_ < 4; ++j_)                                           \
        acc[(IB) + i_][j_] = __builtin_amdgcn_mfma_f32_16x16x32_bf16(          \
            av[i_], bv[j_], acc[(IB) + i_][j_], 0, 0, 0);                      \
    __builtin_amdgcn_s_setprio(0);                                             \
  } while (0)

#define GEMM_TILE(CUR, NXT, TKN, STG) do {                                     \
    /* P0 */                                                                   \
    RD_A(0, CUR, 0); RD_B(CUR, 0);                                             \
    if (STG) { STAGE_A(NXT, TKN, 0); STAGE_B(NXT, TKN, 0); }                   \
    BARR(); LGKM0();                                                           \
    MFMA_BLOCK(0);                                                             \
    BARR();                                                                    \
    /* P1 */                                                                   \
    RD_A(4, CUR, 0);                                                           \
    if (STG) { STAGE_A(NXT, TKN, 1); STAGE_B(NXT, TKN, 1); VMCNT4(); }         \
    else     { VMCNT0(); }                                                     \
    BARR(); LGKM0();                                                           \
    MFMA_BLOCK(4);                                                             \
    BARR();                                                                    \
    /* P2 */                                                                   \
    RD_A(0, CUR, 1); RD_B(CUR, 1);                                             \
    if (STG) { STAGE_A(NXT, TKN, 2); STAGE_B(NXT, TKN, 2); }                   \
    BARR(); LGKM0();                                                           \
    MFMA_BLOCK(0);                                                             \
    BARR();                                                                    \
    /* P3 */                                                                   \
    RD_A(4, CUR, 1);                                                           \
    if (STG) { STAGE_A(NXT, TKN, 3); STAGE_B(NXT, TKN, 3); VMCNT4(); }         \
    BARR(); LGKM0();                                                           \
    MFMA_BLOCK(4);                                                             \
    BARR();                                                                    \
  } while (0)

  f32x4 acc[8][4] = {};
  bf16x8 av[4], bv[4];

  // prologue: stage tile 0 (ks0 chunks first), keep ks1 chunks in flight
  STAGE_A(0, 0, 0); STAGE_B(0, 0, 0);
  STAGE_A(0, 0, 1); STAGE_B(0, 0, 1);
  STAGE_A(0, 0, 2); STAGE_B(0, 0, 2);
  STAGE_A(0, 0, 3); STAGE_B(0, 0, 3);
  VMCNT4();
  BARR();

  for (int tk = 0; tk < NT - 1; ++tk) {
    const int cur = tk & 1;
    GEMM_TILE(cur, cur ^ 1, tk + 1, 1);
  }
  // epilogue tile (NT-1 = 63 -> cur = 1), no staging
  GEMM_TILE(1, 0, 0, 0);

  // C-write: C row = lq*4+rr, C col = lr (verified layout)
  #pragma unroll
  for (int i = 0; i < 8; ++i)
    #pragma unroll
    for (int j = 0; j < 4; ++j)
      #pragma unroll
      for (int rr = 0; rr < 4; ++rr) {
        int mm = m0 + wm + i * 16 + lq * 4 + rr;
        int nn = n0 + wn + j * 16 + lr;
        out[(size_t)mm * NDIM + nn] = acc[i][j][rr];
      }

#undef STAGE_A
#undef STAGE_B
#undef RD_A
#undef RD_B
#undef MFMA_BLOCK
#undef GEMM_TILE
}

extern "C" void kernel_launch(void* const* d_in, const int* in_sizes, int n_in,
                              void* d_out, int out_size, void* d_ws, size_t ws_size,
                              hipStream_t stream) {
  const float* x  = (const float*)d_in[0];   // [4,2048,4096] fp32
  const float* W  = (const float*)d_in[1];   // [4096,4096]
  const float* A  = (const float*)d_in[2];   // [4096,64]
  const float* B  = (const float*)d_in[3];   // [64,4096]
  const float* sv = (const float*)d_in[4];   // [1e6]
  const int*   si = (const int*)d_in[5];     // [2,1e6]
  float* out = (float*)d_out;

  // workspace: S f32 (64MB) | weff bf16 (32MB) | x bf16 (64MB)
  float*  S     = (float*)d_ws;
  bf16_t* weffb = (bf16_t*)(S + (size_t)D_OUT * D_IN);
  bf16_t* xb    = weffb + (size_t)D_OUT * D_IN;

  hipMemsetAsync(S, 0, (size_t)D_OUT * D_IN * sizeof(float), stream);
  scatter_sp_kernel<<<(NNZ + 255) / 256, 256, 0, stream>>>(sv, si, S);
  // fused: 2048 build blocks + 16384 cvt blocks
  build_weff_cvt_kernel<<<2048 + (MTOT * KDIM / 8) / 256, 256, 0, stream>>>(
      W, A, B, S, weffb, x, xb);
  gemm256_kernel<<<dim3((MTOT / BM) * (NDIM / BN)), 512, 0, stream>>>(xb, weffb, out);
}

// Round 3
// 608.137 us; speedup vs baseline: 1.1182x; 1.1100x over previous
//
#include <hip/hip_runtime.h>

#define D_OUT 4096
#define D_IN  4096
#define RANK  64
#define NNZ   1000000
#define MTOT  8192   // 4*2048
#define KDIM  4096
#define NDIM  4096

#define BM 256
#define BN 256
#define BK 64
#define NT (KDIM / BK)   // 64 K-tiles

typedef __bf16 bf16_t;
typedef __bf16 bf16x8 __attribute__((ext_vector_type(8)));
typedef __bf16 bf16x4 __attribute__((ext_vector_type(4)));
typedef float  f32x4  __attribute__((ext_vector_type(4)));

// ---------------- kernel 1: scatter-add sparse COO into S ----------------
__global__ __launch_bounds__(256) void scatter_sp_kernel(
    const float* __restrict__ vals, const int* __restrict__ idx,
    float* __restrict__ S) {
  int i = blockIdx.x * 256 + threadIdx.x;
  if (i < NNZ) {
    int r = idx[i];
    int c = idx[NNZ + i];
    atomicAdd(&S[(size_t)r * D_IN + c], vals[i]);
  }
}

// ------- kernel 2: fused {weffb = bf16(W + A@Bmat + S)} + {xb = bf16(x)} -------
// blocks [0, 2048): build_weff tile (o 64 x d 128); blocks [2048, 18432): cvt.
__global__ __launch_bounds__(256) void build_weff_cvt_kernel(
    const float* __restrict__ W, const float* __restrict__ A,
    const float* __restrict__ B, const float* __restrict__ S,
    bf16_t* __restrict__ outb, const float* __restrict__ x,
    bf16_t* __restrict__ xb) {
  __shared__ float sA[64 * 64];
  const int t = threadIdx.x;

  if (blockIdx.x >= 2048) {
    // ---- cvt part: 16384 blocks * 256 threads * 8 elems ----
    int i = (blockIdx.x - 2048) * 256 + t;
    const f32x4* p = (const f32x4*)x + (size_t)i * 2;
    f32x4 a = p[0], b = p[1];
    bf16x8 o;
    o[0] = (bf16_t)a[0]; o[1] = (bf16_t)a[1]; o[2] = (bf16_t)a[2]; o[3] = (bf16_t)a[3];
    o[4] = (bf16_t)b[0]; o[5] = (bf16_t)b[1]; o[6] = (bf16_t)b[2]; o[7] = (bf16_t)b[3];
    *((bf16x8*)xb + i) = o;
    return;
  }

  // ---- build part: grid (32 d-tiles) x (64 o-tiles) ----
  const int o0 = (blockIdx.x >> 5) * 64;
  const int d0 = (blockIdx.x & 31) * 128;
  const int td = t & 31;     // d-group
  const int to = t >> 5;     // o-group 0..7
  const int d  = d0 + td * 4;

  #pragma unroll
  for (int i = 0; i < 16; ++i)
    sA[t + i * 256] = A[(size_t)o0 * 64 + t + i * 256];
  __syncthreads();

  f32x4 acc[8] = {};
  for (int r = 0; r < 64; ++r) {
    f32x4 bv = *(const f32x4*)&B[(size_t)r * D_IN + d];
    #pragma unroll
    for (int j = 0; j < 8; ++j) {
      float a = sA[(to * 8 + j) * 64 + r];
      acc[j] += a * bv;
    }
  }

  #pragma unroll
  for (int j = 0; j < 8; ++j) {
    int o = o0 + to * 8 + j;
    size_t idx = (size_t)o * D_IN + d;
    f32x4 wv = *(const f32x4*)&W[idx];
    f32x4 sv = *(const f32x4*)&S[idx];
    f32x4 v  = wv + sv + acc[j];
    bf16x4 ob;
    ob[0] = (bf16_t)v[0]; ob[1] = (bf16_t)v[1];
    ob[2] = (bf16_t)v[2]; ob[3] = (bf16_t)v[3];
    *(bf16x4*)&outb[idx] = ob;
  }
}

// ---------------- kernel 3: 256x256 8-phase deep-pipelined GEMM ----------------
// out[M][N] = Xb[M][K] @ Wb[N][K]^T, bf16 in / f32 out.
// R3 fix: COALESCED staging. R1/R2's chunk-major layout made each wave's
// global_load_lds read 32 scattered 32B granules (2048 line-requests/CU/K-tile)
// -> memory-request-rate saturated, MfmaUtil pinned at 160/512 ~ 33%.
// New LDS layout [buf][A|B][ks][h][128 rows][32 k]: 4 consecutive lanes read a
// contiguous 64B row-slice (16 lines/wave-op, 1024 lines/K-tile = half).
// ds_read fragment addr = row*64B + lq*16B: 2-way bank pattern (free, m136),
// no swizzle; global_load_lds dest stays linear (T21 trivially satisfied).
//
// Per K-tile (4 phases, stage tile t+1 into other buffer):
//  P0: rd ks0 A[0-3]+B | stage ks0.h0 (A,B)       | bar lgkm0 | 16 MFMA | bar
//  P1: rd ks0 A[4-7]   | stage ks0.h1 (A,B) vm(4) | bar lgkm0 | 16 MFMA | bar
//  P2: rd ks1 A[0-3]+B | stage ks1.h0 (A,B)       | bar lgkm0 | 16 MFMA | bar
//  P3: rd ks1 A[4-7]   | stage ks1.h1 (A,B) vm(4) | bar lgkm0 | 16 MFMA | bar
// P1's vmcnt(4) completes this tile's ks1 (needed at P2, issued 2-3 phases ago);
// P3's completes next tile's ks0. Never vmcnt(0) in the main loop.

#define SBAR()   __builtin_amdgcn_sched_barrier(0)
#define VMCNT4() do { asm volatile("s_waitcnt vmcnt(4)"); SBAR(); } while (0)
#define VMCNT0() do { asm volatile("s_waitcnt vmcnt(0)"); SBAR(); } while (0)
#define LGKM0()  do { asm volatile("s_waitcnt lgkmcnt(0)"); SBAR(); } while (0)
#define BARR()   do { SBAR(); __builtin_amdgcn_s_barrier(); SBAR(); } while (0)

__global__ __launch_bounds__(512, 2) void gemm256_kernel(
    const bf16_t* __restrict__ Xb, const bf16_t* __restrict__ Wb,
    float* __restrict__ out) {
  // [buf][A=0/B=1][ks 0/1][h 0/1][row 0..127][k 0..31]  = 128 KiB
  __shared__ bf16_t lds[2][2][2][2][128][32];

  const int t    = threadIdx.x;
  const int w    = t >> 6;
  const int lane = t & 63;
  const int lr   = lane & 15;
  const int lq   = lane >> 4;

  // T1: XCD-aware swizzle over the 512-block grid (512 % 8 == 0 -> simple form)
  const int bid  = blockIdx.x;
  const int wgid = (bid & 7) * 64 + (bid >> 3);
  const int m0 = (wgid >> 4) * BM;   // 32 m-tiles (consecutive wgids share m-panel)
  const int n0 = (wgid & 15) * BN;   // 16 n-tiles

  const int wm = (w >> 2) * 128;     // 2 M-wave-rows
  const int wn = (w & 3) * 64;       // 4 N-wave-cols
  const int wmh = wm >> 7;           // A h-index for this wave
  const int wnh = wn >> 7;           // B h-index for this wave
  const int wnr = wn & 64;           // B row base within h-half

  // staging: thread t owns (row = t>>2, 64B k-slice = (t&3)*16B) of each op
  const int srow = t >> 2;
  const int sk   = (t & 3) * 8;      // elems
  const bf16_t* aSrc = Xb + (size_t)(m0 + srow) * KDIM + sk;
  const bf16_t* bSrc = Wb + (size_t)(n0 + srow) * KDIM + sk;

#define STAGE(NXT, MAT, KS, H, TKN)                                            \
  __builtin_amdgcn_global_load_lds(                                            \
      (const __attribute__((address_space(1))) void*)(const void*)             \
          (((MAT) ? bSrc : aSrc) + (size_t)(H) * 128 * KDIM                    \
           + (size_t)(TKN) * BK + (KS) * 32),                                  \
      (__attribute__((address_space(3))) void*)(void*)                         \
          &lds[NXT][MAT][KS][H][srow][sk],                                     \
      16, 0, 0)

#define RD_A(IB, CUR, KS) do {                                                 \
    _Pragma("unroll")                                                          \
    for (int i_ = 0; i_ < 4; ++i_)                                             \
      av[i_] = *(const bf16x8*)&lds[CUR][0][KS][wmh]                           \
                   [((IB) + i_) * 16 + lr][lq * 8];                            \
  } while (0)
#define RD_B(CUR, KS) do {                                                     \
    _Pragma("unroll")                                                          \
    for (int j_ = 0; j_ < 4; ++j_)                                             \
      bv[j_] = *(const bf16x8*)&lds[CUR][1][KS][wnh]                           \
                   [wnr + j_ * 16 + lr][lq * 8];                               \
  } while (0)

#define MFMA_BLOCK(IB) do {                                                    \
    __builtin_amdgcn_s_setprio(1);                                             \
    _Pragma("unroll")                                                          \
    for (int i_ = 0; i_ < 4; ++i_)                                             \
      _Pragma("unroll")                                                        \
      for (int j_ = 0; j_ < 4; ++j_)                                           \
        acc[(IB) + i_][j_] = __builtin_amdgcn_mfma_f32_16x16x32_bf16(          \
            av[i_], bv[j_], acc[(IB) + i_][j_], 0, 0, 0);                      \
    __builtin_amdgcn_s_setprio(0);                                             \
  } while (0)

#define GEMM_TILE(CUR, NXT, TKN, STG) do {                                     \
    /* P0 */                                                                   \
    RD_A(0, CUR, 0); RD_B(CUR, 0);                                             \
    if (STG) { STAGE(NXT, 0, 0, 0, TKN); STAGE(NXT, 1, 0, 0, TKN); }           \
    BARR(); LGKM0();                                                           \
    MFMA_BLOCK(0);                                                             \
    BARR();                                                                    \
    /* P1 */                                                                   \
    RD_A(4, CUR, 0);                                                           \
    if (STG) { STAGE(NXT, 0, 0, 1, TKN); STAGE(NXT, 1, 0, 1, TKN); VMCNT4(); } \
    else     { VMCNT0(); }                                                     \
    BARR(); LGKM0();                                                           \
    MFMA_BLOCK(4);                                                             \
    BARR();                                                                    \
    /* P2 */                                                                   \
    RD_A(0, CUR, 1); RD_B(CUR, 1);                                             \
    if (STG) { STAGE(NXT, 0, 1, 0, TKN); STAGE(NXT, 1, 1, 0, TKN); }           \
    BARR(); LGKM0();                                                           \
    MFMA_BLOCK(0);                                                             \
    BARR();                                                                    \
    /* P3 */                                                                   \
    RD_A(4, CUR, 1);                                                           \
    if (STG) { STAGE(NXT, 0, 1, 1, TKN); STAGE(NXT, 1, 1, 1, TKN); VMCNT4(); } \
    BARR(); LGKM0();                                                           \
    MFMA_BLOCK(4);                                                             \
    BARR();                                                                    \
  } while (0)

  f32x4 acc[8][4] = {};
  bf16x8 av[4], bv[4];

  // prologue: stage tile 0 (ks0 ops first), keep ks1 ops in flight
  STAGE(0, 0, 0, 0, 0); STAGE(0, 1, 0, 0, 0);
  STAGE(0, 0, 0, 1, 0); STAGE(0, 1, 0, 1, 0);
  STAGE(0, 0, 1, 0, 0); STAGE(0, 1, 1, 0, 0);
  STAGE(0, 0, 1, 1, 0); STAGE(0, 1, 1, 1, 0);
  VMCNT4();
  BARR();

  for (int tk = 0; tk < NT - 1; ++tk) {
    const int cur = tk & 1;
    GEMM_TILE(cur, cur ^ 1, tk + 1, 1);
  }
  // epilogue tile (NT-1 = 63 -> cur = 1), no staging
  GEMM_TILE(1, 0, 0, 0);

  // C-write: C row = lq*4+rr, C col = lr (verified layout)
  #pragma unroll
  for (int i = 0; i < 8; ++i)
    #pragma unroll
    for (int j = 0; j < 4; ++j)
      #pragma unroll
      for (int rr = 0; rr < 4; ++rr) {
        int mm = m0 + wm + i * 16 + lq * 4 + rr;
        int nn = n0 + wn + j * 16 + lr;
        out[(size_t)mm * NDIM + nn] = acc[i][j][rr];
      }

#undef STAGE
#undef RD_A
#undef RD_B
#undef MFMA_BLOCK
#undef GEMM_TILE
}

extern "C" void kernel_launch(void* const* d_in, const int* in_sizes, int n_in,
                              void* d_out, int out_size, void* d_ws, size_t ws_size,
                              hipStream_t stream) {
  const float* x  = (const float*)d_in[0];   // [4,2048,4096] fp32
  const float* W  = (const float*)d_in[1];   // [4096,4096]
  const float* A  = (const float*)d_in[2];   // [4096,64]
  const float* B  = (const float*)d_in[3];   // [64,4096]
  const float* sv = (const float*)d_in[4];   // [1e6]
  const int*   si = (const int*)d_in[5];     // [2,1e6]
  float* out = (float*)d_out;

  // workspace: S f32 (64MB) | weff bf16 (32MB) | x bf16 (64MB)
  float*  S     = (float*)d_ws;
  bf16_t* weffb = (bf16_t*)(S + (size_t)D_OUT * D_IN);
  bf16_t* xb    = weffb + (size_t)D_OUT * D_IN;

  hipMemsetAsync(S, 0, (size_t)D_OUT * D_IN * sizeof(float), stream);
  scatter_sp_kernel<<<(NNZ + 255) / 256, 256, 0, stream>>>(sv, si, S);
  // fused: 2048 build blocks + 16384 cvt blocks
  build_weff_cvt_kernel<<<2048 + (MTOT * KDIM / 8) / 256, 256, 0, stream>>>(
      W, A, B, S, weffb, x, xb);
  gemm256_kernel<<<dim3((MTOT / BM) * (NDIM / BN)), 512, 0, stream>>>(xb, weffb, out);
}

// Round 4
// 600.662 us; speedup vs baseline: 1.1321x; 1.0124x over previous
//
#include <hip/hip_runtime.h>

#define D_OUT 4096
#define D_IN  4096
#define RANK  64
#define NNZ   1000000
#define MTOT  8192   // 4*2048
#define KDIM  4096
#define NDIM  4096

#define BM 256
#define BN 256
#define BK 64
#define NT (KDIM / BK)   // 64 K-tiles

typedef __bf16 bf16_t;
typedef __bf16 bf16x8 __attribute__((ext_vector_type(8)));
typedef __bf16 bf16x4 __attribute__((ext_vector_type(4)));
typedef float  f32x4  __attribute__((ext_vector_type(4)));

// ---------------- kernel 1: scatter-add sparse COO into S ----------------
__global__ __launch_bounds__(256) void scatter_sp_kernel(
    const float* __restrict__ vals, const int* __restrict__ idx,
    float* __restrict__ S) {
  int i = blockIdx.x * 256 + threadIdx.x;
  if (i < NNZ) {
    int r = idx[i];
    int c = idx[NNZ + i];
    atomicAdd(&S[(size_t)r * D_IN + c], vals[i]);
  }
}

// ------- kernel 2: fused {weffb = bf16(W + A@Bmat + S)} + {xb = bf16(x)} -------
// blocks [0, 2048): build_weff tile (o 64 x d 128); blocks [2048, 18432): cvt.
__global__ __launch_bounds__(256) void build_weff_cvt_kernel(
    const float* __restrict__ W, const float* __restrict__ A,
    const float* __restrict__ B, const float* __restrict__ S,
    bf16_t* __restrict__ outb, const float* __restrict__ x,
    bf16_t* __restrict__ xb) {
  __shared__ float sA[64 * 64];
  const int t = threadIdx.x;

  if (blockIdx.x >= 2048) {
    // ---- cvt part: 16384 blocks * 256 threads * 8 elems ----
    int i = (blockIdx.x - 2048) * 256 + t;
    const f32x4* p = (const f32x4*)x + (size_t)i * 2;
    f32x4 a = p[0], b = p[1];
    bf16x8 o;
    o[0] = (bf16_t)a[0]; o[1] = (bf16_t)a[1]; o[2] = (bf16_t)a[2]; o[3] = (bf16_t)a[3];
    o[4] = (bf16_t)b[0]; o[5] = (bf16_t)b[1]; o[6] = (bf16_t)b[2]; o[7] = (bf16_t)b[3];
    *((bf16x8*)xb + i) = o;
    return;
  }

  // ---- build part: grid (32 d-tiles) x (64 o-tiles) ----
  const int o0 = (blockIdx.x >> 5) * 64;
  const int d0 = (blockIdx.x & 31) * 128;
  const int td = t & 31;     // d-group
  const int to = t >> 5;     // o-group 0..7
  const int d  = d0 + td * 4;

  #pragma unroll
  for (int i = 0; i < 16; ++i)
    sA[t + i * 256] = A[(size_t)o0 * 64 + t + i * 256];
  __syncthreads();

  f32x4 acc[8] = {};
  for (int r = 0; r < 64; ++r) {
    f32x4 bv = *(const f32x4*)&B[(size_t)r * D_IN + d];
    #pragma unroll
    for (int j = 0; j < 8; ++j) {
      float a = sA[(to * 8 + j) * 64 + r];
      acc[j] += a * bv;
    }
  }

  #pragma unroll
  for (int j = 0; j < 8; ++j) {
    int o = o0 + to * 8 + j;
    size_t idx = (size_t)o * D_IN + d;
    f32x4 wv = *(const f32x4*)&W[idx];
    f32x4 sv = *(const f32x4*)&S[idx];
    f32x4 v  = wv + sv + acc[j];
    bf16x4 ob;
    ob[0] = (bf16_t)v[0]; ob[1] = (bf16_t)v[1];
    ob[2] = (bf16_t)v[2]; ob[3] = (bf16_t)v[3];
    *(bf16x4*)&outb[idx] = ob;
  }
}

// ---------------- kernel 3: 256x256 8-phase deep-pipelined GEMM ----------------
// out[M][N] = Xb[M][K] @ Wb[N][K]^T, bf16 in / f32 out.
// R4 fix: T2 XOR-swizzle on the 16B slot index. R3's read addr row*64B + lq*16B
// was an 8-WAY bank conflict (64B row stride aliases rows mod 2; 8 even-lr lanes
// per slot class) -> SQ_LDS_BANK_CONFLICT 2.5e7, ~14% of runtime.
// Now: read slot = lq ^ ((lr>>1)&3)  -> even-lr lanes spread over slots 0-3
// (banks 0-15, 2-way = free), odd-lr over banks 16-31. Per T21, LDS dest stays
// LINEAR (t*16B) and the global SOURCE is pre-swizzled: thread t loads k-slice
// (t&3)^((t>>3)&3) — a permutation within the same contiguous 64B segment, so
// coalescing (16 lines/wave-op) is unchanged.
//
// Per K-tile (4 phases, stage tile t+1 into other buffer):
//  P0: rd ks0 A[0-3]+B | stage ks0.h0 (A,B)       | bar lgkm0 | 16 MFMA | bar
//  P1: rd ks0 A[4-7]   | stage ks0.h1 (A,B) vm(4) | bar lgkm0 | 16 MFMA | bar
//  P2: rd ks1 A[0-3]+B | stage ks1.h0 (A,B)       | bar lgkm0 | 16 MFMA | bar
//  P3: rd ks1 A[4-7]   | stage ks1.h1 (A,B) vm(4) | bar lgkm0 | 16 MFMA | bar
// P1's vmcnt(4) completes this tile's ks1 (needed at P2); P3's completes next
// tile's ks0. Never vmcnt(0) in the main loop.

#define SBAR()   __builtin_amdgcn_sched_barrier(0)
#define VMCNT4() do { asm volatile("s_waitcnt vmcnt(4)"); SBAR(); } while (0)
#define VMCNT0() do { asm volatile("s_waitcnt vmcnt(0)"); SBAR(); } while (0)
#define LGKM0()  do { asm volatile("s_waitcnt lgkmcnt(0)"); SBAR(); } while (0)
#define BARR()   do { SBAR(); __builtin_amdgcn_s_barrier(); SBAR(); } while (0)

__global__ __launch_bounds__(512, 2) void gemm256_kernel(
    const bf16_t* __restrict__ Xb, const bf16_t* __restrict__ Wb,
    float* __restrict__ out) {
  // [buf][A=0/B=1][ks 0/1][h 0/1][row 0..127][k 0..31]  = 128 KiB
  __shared__ bf16_t lds[2][2][2][2][128][32];

  const int t    = threadIdx.x;
  const int w    = t >> 6;
  const int lane = t & 63;
  const int lr   = lane & 15;
  const int lq   = lane >> 4;
  // T2: swizzled 16B-slot index for fragment reads (elems offset)
  const int kofs = (lq ^ ((lr >> 1) & 3)) * 8;

  // T1: XCD-aware swizzle over the 512-block grid (512 % 8 == 0 -> simple form)
  const int bid  = blockIdx.x;
  const int wgid = (bid & 7) * 64 + (bid >> 3);
  const int m0 = (wgid >> 4) * BM;   // 32 m-tiles (consecutive wgids share m-panel)
  const int n0 = (wgid & 15) * BN;   // 16 n-tiles

  const int wm = (w >> 2) * 128;     // 2 M-wave-rows
  const int wn = (w & 3) * 64;       // 4 N-wave-cols
  const int wmh = wm >> 7;           // A h-index for this wave
  const int wnh = wn >> 7;           // B h-index for this wave
  const int wnr = wn & 64;           // B row base within h-half

  // staging: thread t owns (row = t>>2, swizzled 16B k-slice) of each op.
  // Source slice g = (t&3) ^ ((t>>3)&3) so that LDS slot s of row r holds
  // global slice s ^ ((r>>1)&3); LDS dest stays linear (t*16B).
  const int srow = t >> 2;
  const int sg   = (((t & 3) ^ ((t >> 3) & 3))) * 8;  // global k-slice, elems
  const int sd   = (t & 3) * 8;                       // linear LDS slot, elems
  const bf16_t* aSrc = Xb + (size_t)(m0 + srow) * KDIM + sg;
  const bf16_t* bSrc = Wb + (size_t)(n0 + srow) * KDIM + sg;

#define STAGE(NXT, MAT, KS, H, TKN)                                            \
  __builtin_amdgcn_global_load_lds(                                            \
      (const __attribute__((address_space(1))) void*)(const void*)             \
          (((MAT) ? bSrc : aSrc) + (size_t)(H) * 128 * KDIM                    \
           + (size_t)(TKN) * BK + (KS) * 32),                                  \
      (__attribute__((address_space(3))) void*)(void*)                         \
          &lds[NXT][MAT][KS][H][srow][sd],                                     \
      16, 0, 0)

#define RD_A(IB, CUR, KS) do {                                                 \
    _Pragma("unroll")                                                          \
    for (int i_ = 0; i_ < 4; ++i_)                                             \
      av[i_] = *(const bf16x8*)&lds[CUR][0][KS][wmh]                           \
                   [((IB) + i_) * 16 + lr][kofs];                              \
  } while (0)
#define RD_B(CUR, KS) do {                                                     \
    _Pragma("unroll")                                                          \
    for (int j_ = 0; j_ < 4; ++j_)                                             \
      bv[j_] = *(const bf16x8*)&lds[CUR][1][KS][wnh]                           \
                   [wnr + j_ * 16 + lr][kofs];                                 \
  } while (0)

#define MFMA_BLOCK(IB) do {                                                    \
    __builtin_amdgcn_s_setprio(1);                                             \
    _Pragma("unroll")                                                          \
    for (int i_ = 0; i_ < 4; ++i_)                                             \
      _Pragma("unroll")                                                        \
      for (int j_ = 0; j_ < 4; ++j_)                                           \
        acc[(IB) + i_][j_] = __builtin_amdgcn_mfma_f32_16x16x32_bf16(          \
            av[i_], bv[j_], acc[(IB) + i_][j_], 0, 0, 0);                      \
    __builtin_amdgcn_s_setprio(0);                                             \
  } while (0)

#define GEMM_TILE(CUR, NXT, TKN, STG) do {                                     \
    /* P0 */                                                                   \
    RD_A(0, CUR, 0); RD_B(CUR, 0);                                             \
    if (STG) { STAGE(NXT, 0, 0, 0, TKN); STAGE(NXT, 1, 0, 0, TKN); }           \
    BARR(); LGKM0();                                                           \
    MFMA_BLOCK(0);                                                             \
    BARR();                                                                    \
    /* P1 */                                                                   \
    RD_A(4, CUR, 0);                                                           \
    if (STG) { STAGE(NXT, 0, 0, 1, TKN); STAGE(NXT, 1, 0, 1, TKN); VMCNT4(); } \
    else     { VMCNT0(); }                                                     \
    BARR(); LGKM0();                                                           \
    MFMA_BLOCK(4);                                                             \
    BARR();                                                                    \
    /* P2 */                                                                   \
    RD_A(0, CUR, 1); RD_B(CUR, 1);                                             \
    if (STG) { STAGE(NXT, 0, 1, 0, TKN); STAGE(NXT, 1, 1, 0, TKN); }           \
    BARR(); LGKM0();                                                           \
    MFMA_BLOCK(0);                                                             \
    BARR();                                                                    \
    /* P3 */                                                                   \
    RD_A(4, CUR, 1);                                                           \
    if (STG) { STAGE(NXT, 0, 1, 1, TKN); STAGE(NXT, 1, 1, 1, TKN); VMCNT4(); } \
    BARR(); LGKM0();                                                           \
    MFMA_BLOCK(4);                                                             \
    BARR();                                                                    \
  } while (0)

  f32x4 acc[8][4] = {};
  bf16x8 av[4], bv[4];

  // prologue: stage tile 0 (ks0 ops first), keep ks1 ops in flight
  STAGE(0, 0, 0, 0, 0); STAGE(0, 1, 0, 0, 0);
  STAGE(0, 0, 0, 1, 0); STAGE(0, 1, 0, 1, 0);
  STAGE(0, 0, 1, 0, 0); STAGE(0, 1, 1, 0, 0);
  STAGE(0, 0, 1, 1, 0); STAGE(0, 1, 1, 1, 0);
  VMCNT4();
  BARR();

  for (int tk = 0; tk < NT - 1; ++tk) {
    const int cur = tk & 1;
    GEMM_TILE(cur, cur ^ 1, tk + 1, 1);
  }
  // epilogue tile (NT-1 = 63 -> cur = 1), no staging
  GEMM_TILE(1, 0, 0, 0);

  // C-write: C row = lq*4+rr, C col = lr (verified layout)
  #pragma unroll
  for (int i = 0; i < 8; ++i)
    #pragma unroll
    for (int j = 0; j < 4; ++j)
      #pragma unroll
      for (int rr = 0; rr < 4; ++rr) {
        int mm = m0 + wm + i * 16 + lq * 4 + rr;
        int nn = n0 + wn + j * 16 + lr;
        out[(size_t)mm * NDIM + nn] = acc[i][j][rr];
      }

#undef STAGE
#undef RD_A
#undef RD_B
#undef MFMA_BLOCK
#undef GEMM_TILE
}

extern "C" void kernel_launch(void* const* d_in, const int* in_sizes, int n_in,
                              void* d_out, int out_size, void* d_ws, size_t ws_size,
                              hipStream_t stream) {
  const float* x  = (const float*)d_in[0];   // [4,2048,4096] fp32
  const float* W  = (const float*)d_in[1];   // [4096,4096]
  const float* A  = (const float*)d_in[2];   // [4096,64]
  const float* B  = (const float*)d_in[3];   // [64,4096]
  const float* sv = (const float*)d_in[4];   // [1e6]
  const int*   si = (const int*)d_in[5];     // [2,1e6]
  float* out = (float*)d_out;

  // workspace: S f32 (64MB) | weff bf16 (32MB) | x bf16 (64MB)
  float*  S     = (float*)d_ws;
  bf16_t* weffb = (bf16_t*)(S + (size_t)D_OUT * D_IN);
  bf16_t* xb    = weffb + (size_t)D_OUT * D_IN;

  hipMemsetAsync(S, 0, (size_t)D_OUT * D_IN * sizeof(float), stream);
  scatter_sp_kernel<<<(NNZ + 255) / 256, 256, 0, stream>>>(sv, si, S);
  // fused: 2048 build blocks + 16384 cvt blocks
  build_weff_cvt_kernel<<<2048 + (MTOT * KDIM / 8) / 256, 256, 0, stream>>>(
      W, A, B, S, weffb, x, xb);
  gemm256_kernel<<<dim3((MTOT / BM) * (NDIM / BN)), 512, 0, stream>>>(xb, weffb, out);
}